// Round 8
// baseline (472.533 us; speedup 1.0000x reference)
//
#include <hip/hip_runtime.h>

typedef unsigned short u16;
typedef __attribute__((ext_vector_type(8))) short short8;
typedef __attribute__((ext_vector_type(4))) float floatx4;

#define B_  16
#define S_  384
#define D_  768
#define H_  12
#define DH_ 64
#define FF_ 3072

__device__ __forceinline__ float b2f(u16 h) { return __uint_as_float(((unsigned)h) << 16); }
__device__ __forceinline__ u16 f2b(float f) {
  unsigned u = __float_as_uint(f);
  u += 0x7fffu + ((u >> 16) & 1u);
  return (u16)(u >> 16);
}

__device__ __forceinline__ void gload16(const u16* g, u16* l) {
  __builtin_amdgcn_global_load_lds(
      (const __attribute__((address_space(1))) unsigned int*)g,
      (__attribute__((address_space(3))) unsigned int*)l, 16, 0, 0);
}

__global__ __launch_bounds__(256) void fill_sentinel(u16* out, int n) {
  int i = blockIdx.x * 256 + threadIdx.x;
  if (i < n) out[i] = 0x42DE;  // bf16 111.0
}

// ---------------- dtype detect ----------------
__global__ __launch_bounds__(256) void detect_dtype(const u16* __restrict__ x, int* flag) {
  __shared__ int cnt;
  if (threadIdx.x == 0) cnt = 0;
  __syncthreads();
  int c = 0;
  for (int i = threadIdx.x; i < 8192; i += 256) {
    const unsigned e = (x[i] >> 7) & 0xFFu;
    if (e >= 0xC0u) ++c;
  }
  atomicAdd(&cnt, c);
  __syncthreads();
  if (threadIdx.x == 0) *flag = (cnt > 64) ? 1 : 0;  // 1 = fp32 inputs
}

// ---------------- x/pe conversion, 4-wide ----------------
__global__ __launch_bounds__(256) void convert_in4(const void* __restrict__ src,
                                                   u16* __restrict__ dst, int n4,
                                                   const int* __restrict__ flag) {
  const int i = blockIdx.x * 256 + threadIdx.x;
  if (i >= n4) return;
  if (*flag) {
    const float4 f = ((const float4*)src)[i];
    ushort4 o;
    o.x = f2b(f.x); o.y = f2b(f.y); o.z = f2b(f.z); o.w = f2b(f.w);
    ((ushort4*)dst)[i] = o;
  } else {
    ((ushort4*)dst)[i] = ((const ushort4*)src)[i];
  }
}

// ---------------- all small tensors in one launch (8448 elems) ----------------
__global__ __launch_bounds__(256) void convert_small(
    const void* b1, const void* ub, const void* vb, const void* b2,
    const void* g1, const void* be1, const void* g2, const void* be2,
    u16* b1c, u16* ubc, u16* vbc, u16* b2c,
    u16* g1c, u16* be1c, u16* g2c, u16* be2c, const int* __restrict__ flag) {
  const int i = blockIdx.x * 256 + threadIdx.x;
  if (i >= 8448) return;
  const void* s; u16* d; int off;
  if (i < 3072) { s = b1; d = b1c; off = i; }
  else {
    const int r = i - 3072, sg = r / 768; off = r - sg * 768;
    switch (sg) {
      case 0: s = ub;  d = ubc;  break;
      case 1: s = vb;  d = vbc;  break;
      case 2: s = b2;  d = b2c;  break;
      case 3: s = g1;  d = g1c;  break;
      case 4: s = be1; d = be1c; break;
      case 5: s = g2;  d = g2c;  break;
      default: s = be2; d = be2c; break;
    }
  }
  d[off] = (*flag) ? f2b(((const float*)s)[off]) : ((const u16*)s)[off];
}

// ---------------- all 7 weight transposes in one launch ----------------
struct TP { const void* src[7]; u16* dst[7]; };
__global__ __launch_bounds__(256) void transpose_all(TP tp, const int* __restrict__ flag) {
  __shared__ u16 t[32][33];
  const int f32 = *flag;
  const int id = blockIdx.x;
  int w, tt, R, C, bc, br;
  if (id < 2880)      { w = id / 576; tt = id % 576;  R = 768;  C = 768;  bc = (tt % 24) * 32; br = (tt / 24) * 32; }
  else if (id < 5184) { w = 5;        tt = id - 2880; R = 768;  C = 3072; bc = (tt % 96) * 32; br = (tt / 96) * 32; }
  else                { w = 6;        tt = id - 5184; R = 3072; C = 768;  bc = (tt % 24) * 32; br = (tt / 24) * 32; }
  const void* in = tp.src[w];
  u16* out = tp.dst[w];
  const int tx = threadIdx.x & 31, ty = threadIdx.x >> 5;
  for (int i = ty; i < 32; i += 8) {
    const size_t idx = (size_t)(br + i) * C + bc + tx;
    t[i][tx] = f32 ? f2b(((const float*)in)[idx]) : ((const u16*)in)[idx];
  }
  __syncthreads();
  for (int i = ty; i < 32; i += 8) out[(size_t)(bc + i) * R + br + tx] = t[tx][i];
}

// ---------------- GEMM v3 (verified r5): XOR-swizzled LDS + prefetch ----------------
enum { F_BIAS = 1, F_RELU = 2, F_RES = 4, F_QKV = 8 };

template <int TM, int TN, int WM, int WN, int FLAGS>
__global__ __launch_bounds__(256) void gemm3(
    const u16* __restrict__ A, const u16* __restrict__ Bt,
    u16* __restrict__ out0, u16* __restrict__ out1,
    u16* __restrict__ out2, u16* __restrict__ out3,
    const u16* __restrict__ bias0, const u16* __restrict__ bias1,
    const u16* __restrict__ res, int M, int N, int K) {
  constexpr int WAVES_M = TM / WM;
  constexpr int MT = WM / 16, NT = WN / 16;
  constexpr int NI = (TM + TN) / 64;
  static_assert((TM / WM) * (TN / WN) == 4, "4 waves");
  __shared__ u16 SM[2][(TM + TN) * 32];

  const int m0 = blockIdx.y * TM;
  const int n0 = blockIdx.x * TN;
  const int tid = threadIdx.x;
  const int wid = tid >> 6, lane = tid & 63;
  const int wm = (wid % WAVES_M) * WM, wn = (wid / WAVES_M) * WN;
  const int lm = lane & 15, quad = lane >> 4;

  floatx4 acc[MT][NT];
#pragma unroll
  for (int i = 0; i < MT; ++i)
#pragma unroll
    for (int j = 0; j < NT; ++j) acc[i][j] = (floatx4){0.f, 0.f, 0.f, 0.f};

  const u16* srcs[NI];
  int ldso[NI];
#pragma unroll
  for (int i = 0; i < NI; ++i) {
    const int j = wid + 4 * i;
    const int r = j * 16 + (lane >> 2);
    const int q = (lane & 3) ^ ((r >> 1) & 3);
    const u16* p;
    if (r < TM) {
      int ga = m0 + r;
      if (ga > M - 1) ga = M - 1;
      p = A + (size_t)ga * K + q * 8;
    } else {
      p = Bt + (size_t)(n0 + r - TM) * K + q * 8;
    }
    srcs[i] = p;
    ldso[i] = j * 512;
  }
  const int slot = (quad ^ ((lm >> 1) & 3)) * 8;
  int aoff[MT], boff[NT];
#pragma unroll
  for (int t = 0; t < MT; ++t) aoff[t] = (wm + t * 16 + lm) * 32 + slot;
#pragma unroll
  for (int t = 0; t < NT; ++t) boff[t] = (TM + wn + t * 16 + lm) * 32 + slot;

#pragma unroll
  for (int i = 0; i < NI; ++i) gload16(srcs[i], &SM[0][ldso[i]]);
  __syncthreads();

  int buf = 0;
  for (int k0 = 0; k0 < K; k0 += 32, buf ^= 1) {
    if (k0 + 32 < K) {
      const int koff = (k0 + 32);
#pragma unroll
      for (int i = 0; i < NI; ++i) gload16(srcs[i] + koff, &SM[buf ^ 1][ldso[i]]);
    }
    short8 af[MT], bf[NT];
#pragma unroll
    for (int t = 0; t < MT; ++t) af[t] = *(const short8*)(&SM[buf][aoff[t]]);
#pragma unroll
    for (int t = 0; t < NT; ++t) bf[t] = *(const short8*)(&SM[buf][boff[t]]);
#pragma unroll
    for (int tm = 0; tm < MT; ++tm)
#pragma unroll
      for (int tn = 0; tn < NT; ++tn)
        acc[tm][tn] = __builtin_amdgcn_mfma_f32_16x16x32_bf16(af[tm], bf[tn], acc[tm][tn], 0, 0, 0);
    __syncthreads();
  }

#pragma unroll
  for (int tm = 0; tm < MT; ++tm) {
#pragma unroll
    for (int tn = 0; tn < NT; ++tn) {
      const int gcol = n0 + wn + tn * 16 + lm;
#pragma unroll
      for (int r = 0; r < 4; ++r) {
        const int grow = m0 + wm + tm * 16 + quad * 4 + r;
        if (grow >= M) continue;
        float val = acc[tm][tn][r];
        if (FLAGS & F_QKV) {
          const int region = gcol / 768;
          const int c = gcol - region * 768;
          if (region == 0) {
            out0[(size_t)grow * 768 + c] = f2b(val + b2f(bias0[c]));
            out1[(size_t)grow * 768 + c] = f2b(val + b2f(bias1[c]));
          } else if (region == 1) {
            out2[(size_t)grow * 768 + c] = f2b(val);
          } else {
            const int bb = grow / S_, s = grow - bb * S_;
            out3[((size_t)bb * D_ + c) * S_ + s] = f2b(val);
          }
        } else {
          if (FLAGS & F_BIAS) val += b2f(bias0[gcol]);
          if (FLAGS & F_RES) val += b2f(res[(size_t)grow * N + gcol]);
          if (FLAGS & F_RELU) val = fmaxf(val, 0.f);
          out0[(size_t)grow * N + gcol] = f2b(val);
        }
      }
    }
  }
}

// ---------------- attention v5: 8 waves/block, TLP latency hiding ----------------
// grid 4608 (swizzled: 24 q-tiles of a (b,h) share id%8 -> same XCD), 512 threads.
// LDS 37,952 B -> 4 blocks/CU -> 32 waves/CU = 100% occupancy.
__global__ __launch_bounds__(512, 8) void attn_kernel(
    const u16* __restrict__ qu, const u16* __restrict__ qv,
    const u16* __restrict__ kb, const u16* __restrict__ vt,
    const u16* __restrict__ rb, u16* __restrict__ attn) {
  __shared__ float scA[16 * 388];   // A_C fp32; P (bf16) overlaid per-row slab
  __shared__ u16 Eb[16 * 408];      // B_D bf16; PV partials (float, stride 68) overlaid
  __shared__ float rsum[16];

  const int id = blockIdx.x;
  const int g = id >> 3;
  const int qt = g % 24;
  const int bh = (id & 7) + 8 * (g / 24);
  const int b = bh / H_, h = bh % H_;
  const int i0 = qt * 16;
  const int tid = threadIdx.x, wid = tid >> 6, lane = tid & 63;
  const int lm = lane & 15, quad = lane >> 4;

  const size_t qrow = ((size_t)(b * S_ + i0 + lm)) * D_ + h * DH_;

  // ---- score phase: 49 units (25 B_D + 24 A_C) striped over 8 waves ----
#pragma unroll
  for (int i = 0; i < 7; ++i) {
    const int u = wid + 8 * i;   // wave-uniform
    if (u >= 49) break;
    if (u < 25) {
      int t = i0 + u * 16 + lm;
      if (t > 766) t = 766;  // clamp; those entries are never gathered
      const u16* p = rb + (size_t)t * D_ + h * DH_;
      const short8 b0 = *(const short8*)(p + quad * 8);
      const short8 b1 = *(const short8*)(p + 32 + quad * 8);
      const short8 a0 = *(const short8*)(qv + qrow + quad * 8);
      const short8 a1 = *(const short8*)(qv + qrow + 32 + quad * 8);
      floatx4 e = (floatx4){0.f, 0.f, 0.f, 0.f};
      e = __builtin_amdgcn_mfma_f32_16x16x32_bf16(a0, b0, e, 0, 0, 0);
      e = __builtin_amdgcn_mfma_f32_16x16x32_bf16(a1, b1, e, 0, 0, 0);
#pragma unroll
      for (int r = 0; r < 4; ++r) Eb[(quad * 4 + r) * 408 + u * 16 + lm] = f2b(e[r]);
    } else {
      const int j0 = (u - 25) * 16;
      const u16* p = kb + ((size_t)(b * S_ + j0 + lm)) * D_ + h * DH_;
      const short8 b0 = *(const short8*)(p + quad * 8);
      const short8 b1 = *(const short8*)(p + 32 + quad * 8);
      const short8 a0 = *(const short8*)(qu + qrow + quad * 8);
      const short8 a1 = *(const short8*)(qu + qrow + 32 + quad * 8);
      floatx4 e = (floatx4){0.f, 0.f, 0.f, 0.f};
      e = __builtin_amdgcn_mfma_f32_16x16x32_bf16(a0, b0, e, 0, 0, 0);
      e = __builtin_amdgcn_mfma_f32_16x16x32_bf16(a1, b1, e, 0, 0, 0);
#pragma unroll
      for (int r = 0; r < 4; ++r) scA[(quad * 4 + r) * 388 + j0 + lm] = e[r];
    }
  }
  __syncthreads();  // barrier 1

  // ---- softmax: row = wid*2 + (lane>>5), 32 lanes per row, 12 cols/lane ----
  u16* p16 = (u16*)scA;  // P[row][c] at u16 idx row*776 + c
  {
    const int row = wid * 2 + (lane >> 5);
    const int sub = lane & 31;
    float v[12];
    float lmax = -1e30f;
#pragma unroll
    for (int cc = 0; cc < 12; ++cc) {
      const int c = sub + cc * 32;
      const float s = (scA[row * 388 + c] + b2f(Eb[row * 408 + row + 383 - c])) * 0.125f;
      v[cc] = s;
      lmax = fmaxf(lmax, s);
    }
#pragma unroll
    for (int m = 1; m < 32; m <<= 1) lmax = fmaxf(lmax, __shfl_xor(lmax, m));
    float lsum = 0.f;
#pragma unroll
    for (int cc = 0; cc < 12; ++cc) {
      const float e = __expf(v[cc] - lmax);
      p16[row * 776 + sub + cc * 32] = f2b(e);
      lsum += e;
    }
#pragma unroll
    for (int m = 1; m < 32; m <<= 1) lsum += __shfl_xor(lsum, m);
    if (sub == 0) rsum[row] = lsum;
  }
  __syncthreads();  // barrier 2

  // ---- PV: wave = (dh-tile wid&3, key-half wid>>2); 6 MFMAs each ----
  float* part = (float*)Eb;  // [kh][16 rows][stride 68]
  {
    const int nt = wid & 3, kh = wid >> 2;
    floatx4 o = (floatx4){0.f, 0.f, 0.f, 0.f};
    const size_t vbase = ((size_t)(b * D_ + h * DH_ + nt * 16 + lm)) * S_ + kh * 192;
#pragma unroll
    for (int kk = 0; kk < 6; ++kk) {
      const short8 af = *(const short8*)(&p16[lm * 776 + kh * 192 + kk * 32 + quad * 8]);
      const short8 bv = *(const short8*)(vt + vbase + kk * 32 + quad * 8);
      o = __builtin_amdgcn_mfma_f32_16x16x32_bf16(af, bv, o, 0, 0, 0);
    }
#pragma unroll
    for (int r = 0; r < 4; ++r)
      part[kh * 1088 + (quad * 4 + r) * 68 + nt * 16 + lm] = o[r];
  }
  __syncthreads();  // barrier 3

#pragma unroll
  for (int i = 0; i < 2; ++i) {
    const int idx = tid + 512 * i;
    const int row = idx >> 6, dh = idx & 63;
    const float v = (part[row * 68 + dh] + part[1088 + row * 68 + dh]) / rsum[row];
    attn[((size_t)(b * S_ + i0 + row)) * D_ + h * DH_ + dh] = f2b(v);
  }
}

// ---------------- row layernorm ----------------
__global__ __launch_bounds__(256) void ln_kernel(const u16* __restrict__ y,
                                                 const u16* __restrict__ g,
                                                 const u16* __restrict__ bb,
                                                 void* __restrict__ outv,
                                                 const int* __restrict__ flag, int dual) {
  const int row = blockIdx.x * 4 + (threadIdx.x >> 6);
  const int lane = threadIdx.x & 63;
  const u16* yr = y + (size_t)row * D_;
  float vbuf[12], s = 0.f, s2 = 0.f;
#pragma unroll
  for (int i = 0; i < 12; ++i) {
    const float x = b2f(yr[lane + i * 64]);
    vbuf[i] = x;
    s += x;
    s2 += x * x;
  }
#pragma unroll
  for (int off = 32; off; off >>= 1) {
    s += __shfl_down(s, off);
    s2 += __shfl_down(s2, off);
  }
  s = __shfl(s, 0);
  s2 = __shfl(s2, 0);
  const float mean = s * (1.f / 768.f);
  const float var = s2 * (1.f / 768.f) - mean * mean;
  const float inv = rsqrtf(var + 1e-5f);
  const int f32out = dual && *flag;
#pragma unroll
  for (int i = 0; i < 12; ++i) {
    const int c = lane + i * 64;
    const float val = (vbuf[i] - mean) * inv * b2f(g[c]) + b2f(bb[c]);
    if (f32out) ((float*)outv)[(size_t)row * D_ + c] = val;
    else ((u16*)outv)[(size_t)row * D_ + c] = f2b(val);
  }
}

// ---------------- host ----------------
extern "C" void kernel_launch(void* const* d_in, const int* in_sizes, int n_in,
                              void* d_out, int out_size, void* d_ws, size_t ws_size,
                              hipStream_t stream) {
  const void* x    = d_in[0];
  const void* pe   = d_in[1];
  const void* Wq   = d_in[2];
  const void* Wk   = d_in[3];
  const void* Wv   = d_in[4];
  const void* Wr   = d_in[5];
  const void* ub   = d_in[6];
  const void* vb   = d_in[7];
  const void* Wo   = d_in[8];
  const void* ln1g = d_in[9];
  const void* ln1b = d_in[10];
  const void* ln2g = d_in[11];
  const void* ln2b = d_in[12];
  const void* W1   = d_in[13];
  const void* b1   = d_in[14];
  const void* W2   = d_in[15];
  const void* b2   = d_in[16];
  char* ws = (char*)d_ws;

  constexpr int N_X  = B_ * S_ * D_;
  constexpr int N_PE = (2 * S_ - 1) * D_;

  constexpr size_t O_W   = 0;
  constexpr size_t O_SM  = 15335424;
  constexpr size_t O_XB  = 15368192;
  constexpr size_t O_QU  = 24805376;
  constexpr size_t O_QV  = 34242560;
  constexpr size_t O_KB  = 43679744;
  constexpr size_t O_VT  = 53116928;
  constexpr size_t O_RB  = 62554112;
  constexpr size_t NEEDED = 63733760;

  if (ws_size < NEEDED) {
    fill_sentinel<<<(out_size + 255) / 256, 256, 0, stream>>>((u16*)d_out, out_size);
    return;
  }

  int* flag = (int*)(ws + O_SM);
  u16* ubc  = (u16*)(ws + O_SM + 128);
  u16* vbc  = (u16*)(ws + O_SM + 1664);
  u16* b1c  = (u16*)(ws + O_SM + 3200);
  u16* b2c  = (u16*)(ws + O_SM + 9344);
  u16* g1c  = (u16*)(ws + O_SM + 10880);
  u16* be1c = (u16*)(ws + O_SM + 12416);
  u16* g2c  = (u16*)(ws + O_SM + 13952);
  u16* be2c = (u16*)(ws + O_SM + 15488);

  u16* wtq = (u16*)(ws + O_W);
  u16* wtk = wtq + (size_t)D_ * D_;
  u16* wtv = wtk + (size_t)D_ * D_;
  u16* wtr = wtv + (size_t)D_ * D_;
  u16* wto = wtr + (size_t)D_ * D_;
  u16* wt1 = wto + (size_t)D_ * D_;
  u16* wt2 = wt1 + (size_t)D_ * FF_;

  u16* xb  = (u16*)(ws + O_XB);
  u16* quB = (u16*)(ws + O_QU);
  u16* peb = (u16*)(ws + O_QV);
  u16* qvB = (u16*)(ws + O_QV);
  u16* kbB = (u16*)(ws + O_KB);
  u16* vtB = (u16*)(ws + O_VT);
  u16* rbB = (u16*)(ws + O_RB);
  u16* atB = (u16*)d_out;
  u16* y1B = xb;
  u16* x1B = (u16*)(ws + O_VT);
  u16* ffB = xb;
  u16* y2B = x1B;

  detect_dtype<<<1, 256, 0, stream>>>((const u16*)x, flag);
  convert_in4<<<(N_X / 4 + 255) / 256, 256, 0, stream>>>(x, xb, N_X / 4, flag);
  convert_in4<<<(N_PE / 4 + 255) / 256, 256, 0, stream>>>(pe, peb, N_PE / 4, flag);
  convert_small<<<33, 256, 0, stream>>>(b1, ub, vb, b2, ln1g, ln1b, ln2g, ln2b,
                                        b1c, ubc, vbc, b2c, g1c, be1c, g2c, be2c, flag);
  TP tp;
  tp.src[0] = Wq; tp.src[1] = Wk; tp.src[2] = Wv; tp.src[3] = Wr; tp.src[4] = Wo;
  tp.src[5] = W1; tp.src[6] = W2;
  tp.dst[0] = wtq; tp.dst[1] = wtk; tp.dst[2] = wtv; tp.dst[3] = wtr; tp.dst[4] = wto;
  tp.dst[5] = wt1; tp.dst[6] = wt2;
  transpose_all<<<7488, 256, 0, stream>>>(tp, flag);

  // r-proj: M=767 -> 64x64 tiles
  gemm3<64, 64, 32, 32, 0><<<dim3(12, 12), 256, 0, stream>>>(
      peb, wtr, rbB, nullptr, nullptr, nullptr, nullptr, nullptr, nullptr,
      2 * S_ - 1, D_, D_);
  // fused QKV: N=2304
  gemm3<128, 128, 64, 64, F_QKV><<<dim3(18, 48), 256, 0, stream>>>(
      xb, wtq, quB, qvB, kbB, vtB, ubc, vbc, nullptr, B_ * S_, 2304, D_);
  // attention -> d_out scratch (512-thread blocks, swizzled 1D grid)
  attn_kernel<<<4608, 512, 0, stream>>>(quB, qvB, kbB, vtB, rbB, atB);
  // Wo + residual
  gemm3<64, 128, 32, 64, F_RES><<<dim3(6, 96), 256, 0, stream>>>(
      atB, wto, y1B, nullptr, nullptr, nullptr, nullptr, nullptr, xb, B_ * S_, D_, D_);
  ln_kernel<<<B_ * S_ / 4, 256, 0, stream>>>(y1B, g1c, be1c, x1B, flag, 0);
  // FFN1
  gemm3<128, 128, 64, 64, F_BIAS | F_RELU><<<dim3(24, 48), 256, 0, stream>>>(
      x1B, wt1, ffB, nullptr, nullptr, nullptr, b1c, nullptr, nullptr, B_ * S_, FF_, D_);
  // FFN2
  gemm3<64, 128, 32, 64, F_BIAS | F_RES><<<dim3(6, 96), 256, 0, stream>>>(
      ffB, wt2, y2B, nullptr, nullptr, nullptr, b2c, nullptr, x1B, B_ * S_, D_, FF_);
  ln_kernel<<<B_ * S_ / 4, 256, 0, stream>>>(y2B, g2c, be2c, d_out, flag, 1);
}

// Round 9
// 459.452 us; speedup vs baseline: 1.0285x; 1.0285x over previous
//
#include <hip/hip_runtime.h>

typedef unsigned short u16;
typedef __attribute__((ext_vector_type(8))) short short8;
typedef __attribute__((ext_vector_type(4))) float floatx4;

#define B_  16
#define S_  384
#define D_  768
#define H_  12
#define DH_ 64
#define FF_ 3072

__device__ __forceinline__ float b2f(u16 h) { return __uint_as_float(((unsigned)h) << 16); }
__device__ __forceinline__ u16 f2b(float f) {
  unsigned u = __float_as_uint(f);
  u += 0x7fffu + ((u >> 16) & 1u);
  return (u16)(u >> 16);
}

__device__ __forceinline__ void gload16(const u16* g, u16* l) {
  __builtin_amdgcn_global_load_lds(
      (const __attribute__((address_space(1))) unsigned int*)g,
      (__attribute__((address_space(3))) unsigned int*)l, 16, 0, 0);
}

__global__ __launch_bounds__(256) void fill_sentinel(u16* out, int n) {
  int i = blockIdx.x * 256 + threadIdx.x;
  if (i < n) out[i] = 0x42DE;  // bf16 111.0
}

// ---------------- dtype detect ----------------
__global__ __launch_bounds__(256) void detect_dtype(const u16* __restrict__ x, int* flag) {
  __shared__ int cnt;
  if (threadIdx.x == 0) cnt = 0;
  __syncthreads();
  int c = 0;
  for (int i = threadIdx.x; i < 8192; i += 256) {
    const unsigned e = (x[i] >> 7) & 0xFFu;
    if (e >= 0xC0u) ++c;
  }
  atomicAdd(&cnt, c);
  __syncthreads();
  if (threadIdx.x == 0) *flag = (cnt > 64) ? 1 : 0;  // 1 = fp32 inputs
}

// ---------------- x/pe conversion, 4-wide ----------------
__global__ __launch_bounds__(256) void convert_in4(const void* __restrict__ src,
                                                   u16* __restrict__ dst, int n4,
                                                   const int* __restrict__ flag) {
  const int i = blockIdx.x * 256 + threadIdx.x;
  if (i >= n4) return;
  if (*flag) {
    const float4 f = ((const float4*)src)[i];
    ushort4 o;
    o.x = f2b(f.x); o.y = f2b(f.y); o.z = f2b(f.z); o.w = f2b(f.w);
    ((ushort4*)dst)[i] = o;
  } else {
    ((ushort4*)dst)[i] = ((const ushort4*)src)[i];
  }
}

// ---------------- all small tensors in one launch (8448 elems) ----------------
__global__ __launch_bounds__(256) void convert_small(
    const void* b1, const void* ub, const void* vb, const void* b2,
    const void* g1, const void* be1, const void* g2, const void* be2,
    u16* b1c, u16* ubc, u16* vbc, u16* b2c,
    u16* g1c, u16* be1c, u16* g2c, u16* be2c, const int* __restrict__ flag) {
  const int i = blockIdx.x * 256 + threadIdx.x;
  if (i >= 8448) return;
  const void* s; u16* d; int off;
  if (i < 3072) { s = b1; d = b1c; off = i; }
  else {
    const int r = i - 3072, sg = r / 768; off = r - sg * 768;
    switch (sg) {
      case 0: s = ub;  d = ubc;  break;
      case 1: s = vb;  d = vbc;  break;
      case 2: s = b2;  d = b2c;  break;
      case 3: s = g1;  d = g1c;  break;
      case 4: s = be1; d = be1c; break;
      case 5: s = g2;  d = g2c;  break;
      default: s = be2; d = be2c; break;
    }
  }
  d[off] = (*flag) ? f2b(((const float*)s)[off]) : ((const u16*)s)[off];
}

// ---------------- all 7 weight transposes in one launch ----------------
struct TP { const void* src[7]; u16* dst[7]; };
__global__ __launch_bounds__(256) void transpose_all(TP tp, const int* __restrict__ flag) {
  __shared__ u16 t[32][33];
  const int f32 = *flag;
  const int id = blockIdx.x;
  int w, tt, R, C, bc, br;
  if (id < 2880)      { w = id / 576; tt = id % 576;  R = 768;  C = 768;  bc = (tt % 24) * 32; br = (tt / 24) * 32; }
  else if (id < 5184) { w = 5;        tt = id - 2880; R = 768;  C = 3072; bc = (tt % 96) * 32; br = (tt / 96) * 32; }
  else                { w = 6;        tt = id - 5184; R = 3072; C = 768;  bc = (tt % 24) * 32; br = (tt / 24) * 32; }
  const void* in = tp.src[w];
  u16* out = tp.dst[w];
  const int tx = threadIdx.x & 31, ty = threadIdx.x >> 5;
  for (int i = ty; i < 32; i += 8) {
    const size_t idx = (size_t)(br + i) * C + bc + tx;
    t[i][tx] = f32 ? f2b(((const float*)in)[idx]) : ((const u16*)in)[idx];
  }
  __syncthreads();
  for (int i = ty; i < 32; i += 8) out[(size_t)(bc + i) * R + br + tx] = t[tx][i];
}

// ---------------- GEMM v3 (verified r5): XOR-swizzled LDS + prefetch ----------------
enum { F_BIAS = 1, F_RELU = 2, F_RES = 4, F_QKV = 8 };

template <int TM, int TN, int WM, int WN, int FLAGS>
__global__ __launch_bounds__(256) void gemm3(
    const u16* __restrict__ A, const u16* __restrict__ Bt,
    u16* __restrict__ out0, u16* __restrict__ out1,
    u16* __restrict__ out2, u16* __restrict__ out3,
    const u16* __restrict__ bias0, const u16* __restrict__ bias1,
    const u16* __restrict__ res, int M, int N, int K) {
  constexpr int WAVES_M = TM / WM;
  constexpr int MT = WM / 16, NT = WN / 16;
  constexpr int NI = (TM + TN) / 64;
  static_assert((TM / WM) * (TN / WN) == 4, "4 waves");
  __shared__ u16 SM[2][(TM + TN) * 32];

  const int m0 = blockIdx.y * TM;
  const int n0 = blockIdx.x * TN;
  const int tid = threadIdx.x;
  const int wid = tid >> 6, lane = tid & 63;
  const int wm = (wid % WAVES_M) * WM, wn = (wid / WAVES_M) * WN;
  const int lm = lane & 15, quad = lane >> 4;

  floatx4 acc[MT][NT];
#pragma unroll
  for (int i = 0; i < MT; ++i)
#pragma unroll
    for (int j = 0; j < NT; ++j) acc[i][j] = (floatx4){0.f, 0.f, 0.f, 0.f};

  const u16* srcs[NI];
  int ldso[NI];
#pragma unroll
  for (int i = 0; i < NI; ++i) {
    const int j = wid + 4 * i;
    const int r = j * 16 + (lane >> 2);
    const int q = (lane & 3) ^ ((r >> 1) & 3);
    const u16* p;
    if (r < TM) {
      int ga = m0 + r;
      if (ga > M - 1) ga = M - 1;
      p = A + (size_t)ga * K + q * 8;
    } else {
      p = Bt + (size_t)(n0 + r - TM) * K + q * 8;
    }
    srcs[i] = p;
    ldso[i] = j * 512;
  }
  const int slot = (quad ^ ((lm >> 1) & 3)) * 8;
  int aoff[MT], boff[NT];
#pragma unroll
  for (int t = 0; t < MT; ++t) aoff[t] = (wm + t * 16 + lm) * 32 + slot;
#pragma unroll
  for (int t = 0; t < NT; ++t) boff[t] = (TM + wn + t * 16 + lm) * 32 + slot;

#pragma unroll
  for (int i = 0; i < NI; ++i) gload16(srcs[i], &SM[0][ldso[i]]);
  __syncthreads();

  int buf = 0;
  for (int k0 = 0; k0 < K; k0 += 32, buf ^= 1) {
    if (k0 + 32 < K) {
      const int koff = (k0 + 32);
#pragma unroll
      for (int i = 0; i < NI; ++i) gload16(srcs[i] + koff, &SM[buf ^ 1][ldso[i]]);
    }
    short8 af[MT], bf[NT];
#pragma unroll
    for (int t = 0; t < MT; ++t) af[t] = *(const short8*)(&SM[buf][aoff[t]]);
#pragma unroll
    for (int t = 0; t < NT; ++t) bf[t] = *(const short8*)(&SM[buf][boff[t]]);
#pragma unroll
    for (int tm = 0; tm < MT; ++tm)
#pragma unroll
      for (int tn = 0; tn < NT; ++tn)
        acc[tm][tn] = __builtin_amdgcn_mfma_f32_16x16x32_bf16(af[tm], bf[tn], acc[tm][tn], 0, 0, 0);
    __syncthreads();
  }

#pragma unroll
  for (int tm = 0; tm < MT; ++tm) {
#pragma unroll
    for (int tn = 0; tn < NT; ++tn) {
      const int gcol = n0 + wn + tn * 16 + lm;
#pragma unroll
      for (int r = 0; r < 4; ++r) {
        const int grow = m0 + wm + tm * 16 + quad * 4 + r;
        if (grow >= M) continue;
        float val = acc[tm][tn][r];
        if (FLAGS & F_QKV) {
          const int region = gcol / 768;
          const int c = gcol - region * 768;
          if (region == 0) {
            out0[(size_t)grow * 768 + c] = f2b(val + b2f(bias0[c]));
            out1[(size_t)grow * 768 + c] = f2b(val + b2f(bias1[c]));
          } else if (region == 1) {
            out2[(size_t)grow * 768 + c] = f2b(val);
          } else {
            const int bb = grow / S_, s = grow - bb * S_;
            out3[((size_t)bb * D_ + c) * S_ + s] = f2b(val);
          }
        } else {
          if (FLAGS & F_BIAS) val += b2f(bias0[gcol]);
          if (FLAGS & F_RES) val += b2f(res[(size_t)grow * N + gcol]);
          if (FLAGS & F_RELU) val = fmaxf(val, 0.f);
          out0[(size_t)grow * N + gcol] = f2b(val);
        }
      }
    }
  }
}

// ---------------- attention v7: 32-query blocks, shared B-frags, 2 barriers ----------------
// grid 2304, 512 threads (8 waves). Each r/k tile load feeds 4 MFMAs (both row-groups).
// LDS ~78 KB -> 2 blocks/CU. Swizzle: 12 q-tiles of a (b,h) share id%8 (same XCD).
__global__ __launch_bounds__(512, 4) void attn_kernel(
    const u16* __restrict__ qu, const u16* __restrict__ qv,
    const u16* __restrict__ kb, const u16* __restrict__ vt,
    const u16* __restrict__ rb, u16* __restrict__ attn) {
  __shared__ float scA[32 * 396];   // A_C fp32 (stride 396: 2-way banks); P bf16 overlaid
  __shared__ u16 Eb[32 * 424];      // B_D bf16, per-group trel base
  __shared__ float rsum[32];

  const int id = blockIdx.x;
  const int g = id >> 3;
  const int qt = g % 12;
  const int bh = (id & 7) + 8 * (g / 12);
  const int b = bh / H_, h = bh % H_;
  const int i0 = qt * 32;
  const int tid = threadIdx.x, wid = tid >> 6, lane = tid & 63;
  const int lm = lane & 15, quad = lane >> 4;

  // q fragments for both 16-row groups (loaded once per wave)
  const size_t qr0 = ((size_t)(b * S_ + i0 + lm)) * D_ + h * DH_;
  const size_t qr1 = qr0 + (size_t)16 * D_;
  const short8 qv0a = *(const short8*)(qv + qr0 + quad * 8);
  const short8 qv0b = *(const short8*)(qv + qr0 + 32 + quad * 8);
  const short8 qv1a = *(const short8*)(qv + qr1 + quad * 8);
  const short8 qv1b = *(const short8*)(qv + qr1 + 32 + quad * 8);
  const short8 qu0a = *(const short8*)(qu + qr0 + quad * 8);
  const short8 qu0b = *(const short8*)(qu + qr0 + 32 + quad * 8);
  const short8 qu1a = *(const short8*)(qu + qr1 + quad * 8);
  const short8 qu1b = *(const short8*)(qu + qr1 + 32 + quad * 8);

  // ---- score phase: 26 B_D r-tiles + 24 A_C k-tiles = 50 units over 8 waves ----
#pragma unroll
  for (int i = 0; i < 7; ++i) {
    const int u = wid + 8 * i;  // wave-uniform
    if (u >= 50) break;
    if (u < 26) {
      const int m = u;
      int t = i0 + 16 * m + lm;
      if (t > 766) t = 766;  // clamp; per-group trel 399 never gathered
      const u16* p = rb + (size_t)t * D_ + h * DH_;
      const short8 b0 = *(const short8*)(p + quad * 8);
      const short8 b1 = *(const short8*)(p + 32 + quad * 8);
      if (m <= 24) {  // group0: trel tile m
        floatx4 e = (floatx4){0.f, 0.f, 0.f, 0.f};
        e = __builtin_amdgcn_mfma_f32_16x16x32_bf16(qv0a, b0, e, 0, 0, 0);
        e = __builtin_amdgcn_mfma_f32_16x16x32_bf16(qv0b, b1, e, 0, 0, 0);
#pragma unroll
        for (int r = 0; r < 4; ++r) Eb[(quad * 4 + r) * 424 + 16 * m + lm] = f2b(e[r]);
      }
      if (m >= 1) {   // group1: trel tile m-1
        floatx4 e = (floatx4){0.f, 0.f, 0.f, 0.f};
        e = __builtin_amdgcn_mfma_f32_16x16x32_bf16(qv1a, b0, e, 0, 0, 0);
        e = __builtin_amdgcn_mfma_f32_16x16x32_bf16(qv1b, b1, e, 0, 0, 0);
#pragma unroll
        for (int r = 0; r < 4; ++r) Eb[(16 + quad * 4 + r) * 424 + 16 * (m - 1) + lm] = f2b(e[r]);
      }
    } else {
      const int j = u - 26;
      const u16* p = kb + ((size_t)(b * S_ + j * 16 + lm)) * D_ + h * DH_;
      const short8 b0 = *(const short8*)(p + quad * 8);
      const short8 b1 = *(const short8*)(p + 32 + quad * 8);
      floatx4 e0 = (floatx4){0.f, 0.f, 0.f, 0.f};
      e0 = __builtin_amdgcn_mfma_f32_16x16x32_bf16(qu0a, b0, e0, 0, 0, 0);
      e0 = __builtin_amdgcn_mfma_f32_16x16x32_bf16(qu0b, b1, e0, 0, 0, 0);
      floatx4 e1 = (floatx4){0.f, 0.f, 0.f, 0.f};
      e1 = __builtin_amdgcn_mfma_f32_16x16x32_bf16(qu1a, b0, e1, 0, 0, 0);
      e1 = __builtin_amdgcn_mfma_f32_16x16x32_bf16(qu1b, b1, e1, 0, 0, 0);
#pragma unroll
      for (int r = 0; r < 4; ++r) {
        scA[(quad * 4 + r) * 396 + j * 16 + lm] = e0[r];
        scA[(16 + quad * 4 + r) * 396 + j * 16 + lm] = e1[r];
      }
    }
  }
  __syncthreads();  // barrier 1

  // ---- softmax: row = wid*4+quad (0..31), 16 lm-lanes, 24 cols/lane ----
  u16* p16 = (u16*)scA;  // P[row][c] at u16 idx row*792 + c
  {
    const int row = wid * 4 + quad;
    const int rbase = row * 424 + (row & 15) + 383;
    float v[24];
    float lmax = -1e30f;
#pragma unroll
    for (int cc = 0; cc < 24; ++cc) {
      const int c = lm + cc * 16;
      const float s = (scA[row * 396 + c] + b2f(Eb[rbase - c])) * 0.125f;
      v[cc] = s;
      lmax = fmaxf(lmax, s);
    }
#pragma unroll
    for (int m = 1; m < 16; m <<= 1) lmax = fmaxf(lmax, __shfl_xor(lmax, m));
    float lsum = 0.f;
#pragma unroll
    for (int cc = 0; cc < 24; ++cc) {
      const float e = __expf(v[cc] - lmax);
      p16[row * 792 + lm + cc * 16] = f2b(e);
      lsum += e;
    }
#pragma unroll
    for (int m = 1; m < 16; m <<= 1) lsum += __shfl_xor(lsum, m);
    if (lm == 0) rsum[row] = lsum;
  }
  __syncthreads();  // barrier 2

  // ---- PV: wave = (rowgroup wid&1, dh-tile wid>>1); full 384 keys -> direct store ----
  {
    const int rg = wid & 1, nt = wid >> 1;
    floatx4 o = (floatx4){0.f, 0.f, 0.f, 0.f};
    const size_t vbase = ((size_t)(b * D_ + h * DH_ + nt * 16 + lm)) * S_;
    const int pbase = (rg * 16 + lm) * 792;
#pragma unroll
    for (int kk = 0; kk < 12; ++kk) {
      const short8 af = *(const short8*)(&p16[pbase + kk * 32 + quad * 8]);
      const short8 bv = *(const short8*)(vt + vbase + kk * 32 + quad * 8);
      o = __builtin_amdgcn_mfma_f32_16x16x32_bf16(af, bv, o, 0, 0, 0);
    }
#pragma unroll
    for (int r = 0; r < 4; ++r) {
      const int row = rg * 16 + quad * 4 + r;
      attn[((size_t)(b * S_ + i0 + row)) * D_ + h * DH_ + nt * 16 + lm] =
          f2b(o[r] / rsum[row]);
    }
  }
}

// ---------------- row layernorm ----------------
__global__ __launch_bounds__(256) void ln_kernel(const u16* __restrict__ y,
                                                 const u16* __restrict__ g,
                                                 const u16* __restrict__ bb,
                                                 void* __restrict__ outv,
                                                 const int* __restrict__ flag, int dual) {
  const int row = blockIdx.x * 4 + (threadIdx.x >> 6);
  const int lane = threadIdx.x & 63;
  const u16* yr = y + (size_t)row * D_;
  float vbuf[12], s = 0.f, s2 = 0.f;
#pragma unroll
  for (int i = 0; i < 12; ++i) {
    const float x = b2f(yr[lane + i * 64]);
    vbuf[i] = x;
    s += x;
    s2 += x * x;
  }
#pragma unroll
  for (int off = 32; off; off >>= 1) {
    s += __shfl_down(s, off);
    s2 += __shfl_down(s2, off);
  }
  s = __shfl(s, 0);
  s2 = __shfl(s2, 0);
  const float mean = s * (1.f / 768.f);
  const float var = s2 * (1.f / 768.f) - mean * mean;
  const float inv = rsqrtf(var + 1e-5f);
  const int f32out = dual && *flag;
#pragma unroll
  for (int i = 0; i < 12; ++i) {
    const int c = lane + i * 64;
    const float val = (vbuf[i] - mean) * inv * b2f(g[c]) + b2f(bb[c]);
    if (f32out) ((float*)outv)[(size_t)row * D_ + c] = val;
    else ((u16*)outv)[(size_t)row * D_ + c] = f2b(val);
  }
}

// ---------------- host ----------------
extern "C" void kernel_launch(void* const* d_in, const int* in_sizes, int n_in,
                              void* d_out, int out_size, void* d_ws, size_t ws_size,
                              hipStream_t stream) {
  const void* x    = d_in[0];
  const void* pe   = d_in[1];
  const void* Wq   = d_in[2];
  const void* Wk   = d_in[3];
  const void* Wv   = d_in[4];
  const void* Wr   = d_in[5];
  const void* ub   = d_in[6];
  const void* vb   = d_in[7];
  const void* Wo   = d_in[8];
  const void* ln1g = d_in[9];
  const void* ln1b = d_in[10];
  const void* ln2g = d_in[11];
  const void* ln2b = d_in[12];
  const void* W1   = d_in[13];
  const void* b1   = d_in[14];
  const void* W2   = d_in[15];
  const void* b2   = d_in[16];
  char* ws = (char*)d_ws;

  constexpr int N_X  = B_ * S_ * D_;
  constexpr int N_PE = (2 * S_ - 1) * D_;

  constexpr size_t O_W   = 0;
  constexpr size_t O_SM  = 15335424;
  constexpr size_t O_XB  = 15368192;
  constexpr size_t O_QU  = 24805376;
  constexpr size_t O_QV  = 34242560;
  constexpr size_t O_KB  = 43679744;
  constexpr size_t O_VT  = 53116928;
  constexpr size_t O_RB  = 62554112;
  constexpr size_t NEEDED = 63733760;

  if (ws_size < NEEDED) {
    fill_sentinel<<<(out_size + 255) / 256, 256, 0, stream>>>((u16*)d_out, out_size);
    return;
  }

  int* flag = (int*)(ws + O_SM);
  u16* ubc  = (u16*)(ws + O_SM + 128);
  u16* vbc  = (u16*)(ws + O_SM + 1664);
  u16* b1c  = (u16*)(ws + O_SM + 3200);
  u16* b2c  = (u16*)(ws + O_SM + 9344);
  u16* g1c  = (u16*)(ws + O_SM + 10880);
  u16* be1c = (u16*)(ws + O_SM + 12416);
  u16* g2c  = (u16*)(ws + O_SM + 13952);
  u16* be2c = (u16*)(ws + O_SM + 15488);

  u16* wtq = (u16*)(ws + O_W);
  u16* wtk = wtq + (size_t)D_ * D_;
  u16* wtv = wtk + (size_t)D_ * D_;
  u16* wtr = wtv + (size_t)D_ * D_;
  u16* wto = wtr + (size_t)D_ * D_;
  u16* wt1 = wto + (size_t)D_ * D_;
  u16* wt2 = wt1 + (size_t)D_ * FF_;

  u16* xb  = (u16*)(ws + O_XB);
  u16* quB = (u16*)(ws + O_QU);
  u16* peb = (u16*)(ws + O_QV);
  u16* qvB = (u16*)(ws + O_QV);
  u16* kbB = (u16*)(ws + O_KB);
  u16* vtB = (u16*)(ws + O_VT);
  u16* rbB = (u16*)(ws + O_RB);
  u16* atB = (u16*)d_out;
  u16* y1B = xb;
  u16* x1B = (u16*)(ws + O_VT);
  u16* ffB = xb;
  u16* y2B = x1B;

  detect_dtype<<<1, 256, 0, stream>>>((const u16*)x, flag);
  convert_in4<<<(N_X / 4 + 255) / 256, 256, 0, stream>>>(x, xb, N_X / 4, flag);
  convert_in4<<<(N_PE / 4 + 255) / 256, 256, 0, stream>>>(pe, peb, N_PE / 4, flag);
  convert_small<<<33, 256, 0, stream>>>(b1, ub, vb, b2, ln1g, ln1b, ln2g, ln2b,
                                        b1c, ubc, vbc, b2c, g1c, be1c, g2c, be2c, flag);
  TP tp;
  tp.src[0] = Wq; tp.src[1] = Wk; tp.src[2] = Wv; tp.src[3] = Wr; tp.src[4] = Wo;
  tp.src[5] = W1; tp.src[6] = W2;
  tp.dst[0] = wtq; tp.dst[1] = wtk; tp.dst[2] = wtv; tp.dst[3] = wtr; tp.dst[4] = wto;
  tp.dst[5] = wt1; tp.dst[6] = wt2;
  transpose_all<<<7488, 256, 0, stream>>>(tp, flag);

  // r-proj: M=767 -> 64x64 tiles
  gemm3<64, 64, 32, 32, 0><<<dim3(12, 12), 256, 0, stream>>>(
      peb, wtr, rbB, nullptr, nullptr, nullptr, nullptr, nullptr, nullptr,
      2 * S_ - 1, D_, D_);
  // fused QKV: N=2304
  gemm3<128, 128, 64, 64, F_QKV><<<dim3(18, 48), 256, 0, stream>>>(
      xb, wtq, quB, qvB, kbB, vtB, ubc, vbc, nullptr, B_ * S_, 2304, D_);
  // attention -> d_out scratch (32-query blocks, 512 threads)
  attn_kernel<<<2304, 512, 0, stream>>>(quB, qvB, kbB, vtB, rbB, atB);
  // Wo + residual
  gemm3<64, 128, 32, 64, F_RES><<<dim3(6, 96), 256, 0, stream>>>(
      atB, wto, y1B, nullptr, nullptr, nullptr, nullptr, nullptr, xb, B_ * S_, D_, D_);
  ln_kernel<<<B_ * S_ / 4, 256, 0, stream>>>(y1B, g1c, be1c, x1B, flag, 0);
  // FFN1
  gemm3<128, 128, 64, 64, F_BIAS | F_RELU><<<dim3(24, 48), 256, 0, stream>>>(
      x1B, wt1, ffB, nullptr, nullptr, nullptr, b1c, nullptr, nullptr, B_ * S_, FF_, D_);
  // FFN2
  gemm3<64, 128, 32, 64, F_BIAS | F_RES><<<dim3(6, 96), 256, 0, stream>>>(
      ffB, wt2, y2B, nullptr, nullptr, nullptr, b2c, nullptr, x1B, B_ * S_, D_, FF_);
  ln_kernel<<<B_ * S_ / 4, 256, 0, stream>>>(y2B, g2c, be2c, d_out, flag, 1);
}

// Round 10
// 426.860 us; speedup vs baseline: 1.1070x; 1.0764x over previous
//
#include <hip/hip_runtime.h>

typedef unsigned short u16;
typedef __attribute__((ext_vector_type(8))) short short8;
typedef __attribute__((ext_vector_type(4))) float floatx4;

#define B_  16
#define S_  384
#define D_  768
#define H_  12
#define DH_ 64
#define FF_ 3072

__device__ __forceinline__ float b2f(u16 h) { return __uint_as_float(((unsigned)h) << 16); }
__device__ __forceinline__ u16 f2b(float f) {
  unsigned u = __float_as_uint(f);
  u += 0x7fffu + ((u >> 16) & 1u);
  return (u16)(u >> 16);
}

__device__ __forceinline__ void gload16(const u16* g, u16* l) {
  __builtin_amdgcn_global_load_lds(
      (const __attribute__((address_space(1))) unsigned int*)g,
      (__attribute__((address_space(3))) unsigned int*)l, 16, 0, 0);
}

__global__ __launch_bounds__(256) void fill_sentinel(u16* out, int n) {
  int i = blockIdx.x * 256 + threadIdx.x;
  if (i < n) out[i] = 0x42DE;  // bf16 111.0
}

// inline dtype detect: 256 u16 of x; fp32 low-halves hit exp>=0xC0 w.p. 0.25
__device__ __forceinline__ int detect_flag(const u16* x, int tid, int* sh) {
  const unsigned e = (x[tid] >> 7) & 0xFFu;
  const unsigned long long m = __ballot(e >= 0xC0u);
  if ((tid & 63) == 0) sh[tid >> 6] = (m != 0ull) ? 1 : 0;
  __syncthreads();
  return sh[0] | sh[1] | sh[2] | sh[3];
}

// ---------------- mega-preamble: transposes + converts + flag, ONE dispatch ----------------
struct TP { const void* src[7]; u16* dst[7]; };
__global__ __launch_bounds__(256) void preamble_all(
    TP tp, const void* x, const void* pe,
    const void* b1, const void* ub, const void* vb, const void* b2,
    const void* g1, const void* be1, const void* g2, const void* be2,
    u16* xb, u16* peb,
    u16* b1c, u16* ubc, u16* vbc, u16* b2c,
    u16* g1c, u16* be1c, u16* g2c, u16* be2c, int* flag_ws) {
  __shared__ u16 t[32][33];
  __shared__ int fl[4];
  const int tid = threadIdx.x;
  const int f32 = detect_flag((const u16*)x, tid, fl);
  const int id = blockIdx.x;
  if (id == 0 && tid == 0) *flag_ws = f32;  // for ln_kernel's output dtype

  if (id < 7488) {  // weight transposes
    int w, tt, R, C, bc, br;
    if (id < 2880)      { w = id / 576; tt = id % 576;  R = 768;  C = 768;  bc = (tt % 24) * 32; br = (tt / 24) * 32; }
    else if (id < 5184) { w = 5;        tt = id - 2880; R = 768;  C = 3072; bc = (tt % 96) * 32; br = (tt / 96) * 32; }
    else                { w = 6;        tt = id - 5184; R = 3072; C = 768;  bc = (tt % 24) * 32; br = (tt / 24) * 32; }
    const void* in = tp.src[w];
    u16* out = tp.dst[w];
    const int tx = tid & 31, ty = tid >> 5;
    for (int i = ty; i < 32; i += 8) {
      const size_t idx = (size_t)(br + i) * C + bc + tx;
      t[i][tx] = f32 ? f2b(((const float*)in)[idx]) : ((const u16*)in)[idx];
    }
    __syncthreads();
    for (int i = ty; i < 32; i += 8) out[(size_t)(bc + i) * R + br + tx] = t[tx][i];
  } else if (id < 12096) {  // x convert (4-wide)
    const int i = (id - 7488) * 256 + tid;
    if (i < B_ * S_ * D_ / 4) {
      if (f32) {
        const float4 f = ((const float4*)x)[i];
        ushort4 o;
        o.x = f2b(f.x); o.y = f2b(f.y); o.z = f2b(f.z); o.w = f2b(f.w);
        ((ushort4*)xb)[i] = o;
      } else {
        ((ushort4*)xb)[i] = ((const ushort4*)x)[i];
      }
    }
  } else if (id < 12672) {  // pe convert
    const int i = (id - 12096) * 256 + tid;
    if (i < (2 * S_ - 1) * D_ / 4) {
      if (f32) {
        const float4 f = ((const float4*)pe)[i];
        ushort4 o;
        o.x = f2b(f.x); o.y = f2b(f.y); o.z = f2b(f.z); o.w = f2b(f.w);
        ((ushort4*)peb)[i] = o;
      } else {
        ((ushort4*)peb)[i] = ((const ushort4*)pe)[i];
      }
    }
  } else {  // small tensors
    const int i = (id - 12672) * 256 + tid;
    if (i < 8448) {
      const void* s; u16* d; int off;
      if (i < 3072) { s = b1; d = b1c; off = i; }
      else {
        const int r = i - 3072, sg = r / 768; off = r - sg * 768;
        switch (sg) {
          case 0: s = ub;  d = ubc;  break;
          case 1: s = vb;  d = vbc;  break;
          case 2: s = b2;  d = b2c;  break;
          case 3: s = g1;  d = g1c;  break;
          case 4: s = be1; d = be1c; break;
          case 5: s = g2;  d = g2c;  break;
          default: s = be2; d = be2c; break;
        }
      }
      d[off] = f32 ? f2b(((const float*)s)[off]) : ((const u16*)s)[off];
    }
  }
}

// ---------------- GEMM v3 (verified r5): XOR-swizzled LDS + prefetch ----------------
enum { F_BIAS = 1, F_RELU = 2, F_RES = 4 };

template <int TM, int TN, int WM, int WN, int FLAGS>
__global__ __launch_bounds__(256) void gemm3(
    const u16* __restrict__ A, const u16* __restrict__ Bt,
    u16* __restrict__ out0, const u16* __restrict__ bias0,
    const u16* __restrict__ res, int M, int N, int K) {
  constexpr int WAVES_M = TM / WM;
  constexpr int MT = WM / 16, NT = WN / 16;
  constexpr int NI = (TM + TN) / 64;
  static_assert((TM / WM) * (TN / WN) == 4, "4 waves");
  __shared__ u16 SM[2][(TM + TN) * 32];

  const int m0 = blockIdx.y * TM;
  const int n0 = blockIdx.x * TN;
  const int tid = threadIdx.x;
  const int wid = tid >> 6, lane = tid & 63;
  const int wm = (wid % WAVES_M) * WM, wn = (wid / WAVES_M) * WN;
  const int lm = lane & 15, quad = lane >> 4;

  floatx4 acc[MT][NT];
#pragma unroll
  for (int i = 0; i < MT; ++i)
#pragma unroll
    for (int j = 0; j < NT; ++j) acc[i][j] = (floatx4){0.f, 0.f, 0.f, 0.f};

  const u16* srcs[NI];
  int ldso[NI];
#pragma unroll
  for (int i = 0; i < NI; ++i) {
    const int j = wid + 4 * i;
    const int r = j * 16 + (lane >> 2);
    const int q = (lane & 3) ^ ((r >> 1) & 3);
    const u16* p;
    if (r < TM) {
      int ga = m0 + r;
      if (ga > M - 1) ga = M - 1;
      p = A + (size_t)ga * K + q * 8;
    } else {
      p = Bt + (size_t)(n0 + r - TM) * K + q * 8;
    }
    srcs[i] = p;
    ldso[i] = j * 512;
  }
  const int slot = (quad ^ ((lm >> 1) & 3)) * 8;
  int aoff[MT], boff[NT];
#pragma unroll
  for (int t = 0; t < MT; ++t) aoff[t] = (wm + t * 16 + lm) * 32 + slot;
#pragma unroll
  for (int t = 0; t < NT; ++t) boff[t] = (TM + wn + t * 16 + lm) * 32 + slot;

#pragma unroll
  for (int i = 0; i < NI; ++i) gload16(srcs[i], &SM[0][ldso[i]]);
  __syncthreads();

  int buf = 0;
  for (int k0 = 0; k0 < K; k0 += 32, buf ^= 1) {
    if (k0 + 32 < K) {
      const int koff = (k0 + 32);
#pragma unroll
      for (int i = 0; i < NI; ++i) gload16(srcs[i] + koff, &SM[buf ^ 1][ldso[i]]);
    }
    short8 af[MT], bf[NT];
#pragma unroll
    for (int t = 0; t < MT; ++t) af[t] = *(const short8*)(&SM[buf][aoff[t]]);
#pragma unroll
    for (int t = 0; t < NT; ++t) bf[t] = *(const short8*)(&SM[buf][boff[t]]);
#pragma unroll
    for (int tm = 0; tm < MT; ++tm)
#pragma unroll
      for (int tn = 0; tn < NT; ++tn)
        acc[tm][tn] = __builtin_amdgcn_mfma_f32_16x16x32_bf16(af[tm], bf[tn], acc[tm][tn], 0, 0, 0);
    __syncthreads();
  }

#pragma unroll
  for (int tm = 0; tm < MT; ++tm) {
#pragma unroll
    for (int tn = 0; tn < NT; ++tn) {
      const int gcol = n0 + wn + tn * 16 + lm;
#pragma unroll
      for (int r = 0; r < 4; ++r) {
        const int grow = m0 + wm + tm * 16 + quad * 4 + r;
        if (grow >= M) continue;
        float val = acc[tm][tn][r];
        if (FLAGS & F_BIAS) val += b2f(bias0[gcol]);
        if (FLAGS & F_RES) val += b2f(res[(size_t)grow * N + gcol]);
        if (FLAGS & F_RELU) val = fmaxf(val, 0.f);
        out0[(size_t)grow * N + gcol] = f2b(val);
      }
    }
  }
}

// ---------------- fused QKV (region epilogue + vt LDS-bounce) + r-proj ----------------
// grid 900: id<864 -> QKV (18x48, N=2304); else -> r-proj (6x6, M=767,N=768).
__global__ __launch_bounds__(256) void gemm_qkv_rp(
    const u16* __restrict__ xb, const u16* __restrict__ wqkv,
    const u16* __restrict__ peb, const u16* __restrict__ wtr,
    u16* __restrict__ qu, u16* __restrict__ qv,
    u16* __restrict__ kbo, u16* __restrict__ vto, u16* __restrict__ rbo,
    const u16* __restrict__ ubias, const u16* __restrict__ vbias) {
  constexpr int TM = 128, TN = 128, WM = 64, WN = 64;
  constexpr int MT = 4, NT = 4, NI = 4;
  __shared__ u16 SM[2][(TM + TN) * 32];

  const int id = blockIdx.x;
  const int qkv = (id < 864) ? 1 : 0;
  int bx, by, M, N;
  const u16 *A, *Bt;
  if (qkv) { bx = id % 18; by = id / 18; M = B_ * S_; N = 2304; A = xb; Bt = wqkv; }
  else     { const int t2 = id - 864; bx = t2 % 6; by = t2 / 6; M = 767; N = 768; A = peb; Bt = wtr; }
  const int K = 768;
  const int m0 = by * TM, n0 = bx * TN;
  const int tid = threadIdx.x;
  const int wid = tid >> 6, lane = tid & 63;
  const int wm = (wid & 1) * WM, wn = (wid >> 1) * WN;
  const int lm = lane & 15, quad = lane >> 4;

  floatx4 acc[MT][NT];
#pragma unroll
  for (int i = 0; i < MT; ++i)
#pragma unroll
    for (int j = 0; j < NT; ++j) acc[i][j] = (floatx4){0.f, 0.f, 0.f, 0.f};

  const u16* srcs[NI];
  int ldso[NI];
#pragma unroll
  for (int i = 0; i < NI; ++i) {
    const int j = wid + 4 * i;
    const int r = j * 16 + (lane >> 2);
    const int q = (lane & 3) ^ ((r >> 1) & 3);
    const u16* p;
    if (r < TM) {
      int ga = m0 + r;
      if (ga > M - 1) ga = M - 1;
      p = A + (size_t)ga * K + q * 8;
    } else {
      p = Bt + (size_t)(n0 + r - TM) * K + q * 8;
    }
    srcs[i] = p;
    ldso[i] = j * 512;
  }
  const int slot = (quad ^ ((lm >> 1) & 3)) * 8;
  int aoff[MT], boff[NT];
#pragma unroll
  for (int t = 0; t < MT; ++t) aoff[t] = (wm + t * 16 + lm) * 32 + slot;
#pragma unroll
  for (int t = 0; t < NT; ++t) boff[t] = (TM + wn + t * 16 + lm) * 32 + slot;

#pragma unroll
  for (int i = 0; i < NI; ++i) gload16(srcs[i], &SM[0][ldso[i]]);
  __syncthreads();

  int buf = 0;
  for (int k0 = 0; k0 < K; k0 += 32, buf ^= 1) {
    if (k0 + 32 < K) {
      const int koff = (k0 + 32);
#pragma unroll
      for (int i = 0; i < NI; ++i) gload16(srcs[i] + koff, &SM[buf ^ 1][ldso[i]]);
    }
    short8 af[MT], bf[NT];
#pragma unroll
    for (int t = 0; t < MT; ++t) af[t] = *(const short8*)(&SM[buf][aoff[t]]);
#pragma unroll
    for (int t = 0; t < NT; ++t) bf[t] = *(const short8*)(&SM[buf][boff[t]]);
#pragma unroll
    for (int tm = 0; tm < MT; ++tm)
#pragma unroll
      for (int tn = 0; tn < NT; ++tn)
        acc[tm][tn] = __builtin_amdgcn_mfma_f32_16x16x32_bf16(af[tm], bf[tn], acc[tm][tn], 0, 0, 0);
    __syncthreads();
  }

  if (!qkv) {  // r-proj plain store
#pragma unroll
    for (int tm = 0; tm < MT; ++tm)
#pragma unroll
      for (int tn = 0; tn < NT; ++tn) {
        const int gcol = n0 + wn + tn * 16 + lm;
#pragma unroll
        for (int r = 0; r < 4; ++r) {
          const int grow = m0 + wm + tm * 16 + quad * 4 + r;
          if (grow < M) rbo[(size_t)grow * 768 + gcol] = f2b(acc[tm][tn][r]);
        }
      }
    return;
  }
  // QKV epilogue; region is block-uniform (768 % 128 == 0)
  const int region = n0 / 768;
  if (region == 2) {
    // vt: coalesced store via per-wave LDS bounce (SM dead after last barrier)
    u16* wbuf = &SM[0][0] + wid * 1088;  // [64][17]
    const int bb = (m0 + wm) / S_;
    const int sbase = (m0 + wm) % S_;
    const int cl = lane >> 2, sc = (lane & 3) * 16;
#pragma unroll
    for (int tn = 0; tn < NT; ++tn) {
#pragma unroll
      for (int tm = 0; tm < MT; ++tm)
#pragma unroll
        for (int r = 0; r < 4; ++r)
          wbuf[(tm * 16 + quad * 4 + r) * 17 + lm] = f2b(acc[tm][tn][r]);
      short8 s0, s1;
#pragma unroll
      for (int j = 0; j < 8; ++j) s0[j] = (short)wbuf[(sc + j) * 17 + cl];
#pragma unroll
      for (int j = 0; j < 8; ++j) s1[j] = (short)wbuf[(sc + 8 + j) * 17 + cl];
      const int cglob = n0 - 1536 + wn + tn * 16 + cl;
      u16* dst = vto + ((size_t)(bb * D_ + cglob)) * S_ + sbase + sc;
      *(short8*)dst = s0;
      *(short8*)(dst + 8) = s1;
    }
    return;
  }
#pragma unroll
  for (int tm = 0; tm < MT; ++tm) {
#pragma unroll
    for (int tn = 0; tn < NT; ++tn) {
      const int gcol = n0 + wn + tn * 16 + lm;
      const int c = gcol - region * 768;
#pragma unroll
      for (int r = 0; r < 4; ++r) {
        const int grow = m0 + wm + tm * 16 + quad * 4 + r;
        const float val = acc[tm][tn][r];
        if (region == 0) {
          qu[(size_t)grow * 768 + c] = f2b(val + b2f(ubias[c]));
          qv[(size_t)grow * 768 + c] = f2b(val + b2f(vbias[c]));
        } else {
          kbo[(size_t)grow * 768 + c] = f2b(val);
        }
      }
    }
  }
}

// ---------------- attention v7 (verified r9) — rolled score loop ----------------
__global__ __launch_bounds__(512, 4) void attn_kernel(
    const u16* __restrict__ qu, const u16* __restrict__ qv,
    const u16* __restrict__ kb, const u16* __restrict__ vt,
    const u16* __restrict__ rb, u16* __restrict__ attn) {
  __shared__ float scA[32 * 396];
  __shared__ u16 Eb[32 * 424];
  __shared__ float rsum[32];

  const int id = blockIdx.x;
  const int g = id >> 3;
  const int qt = g % 12;
  const int bh = (id & 7) + 8 * (g / 12);
  const int b = bh / H_, h = bh % H_;
  const int i0 = qt * 32;
  const int tid = threadIdx.x, wid = tid >> 6, lane = tid & 63;
  const int lm = lane & 15, quad = lane >> 4;

  const size_t qr0 = ((size_t)(b * S_ + i0 + lm)) * D_ + h * DH_;
  const size_t qr1 = qr0 + (size_t)16 * D_;
  const short8 qv0a = *(const short8*)(qv + qr0 + quad * 8);
  const short8 qv0b = *(const short8*)(qv + qr0 + 32 + quad * 8);
  const short8 qv1a = *(const short8*)(qv + qr1 + quad * 8);
  const short8 qv1b = *(const short8*)(qv + qr1 + 32 + quad * 8);
  const short8 qu0a = *(const short8*)(qu + qr0 + quad * 8);
  const short8 qu0b = *(const short8*)(qu + qr0 + 32 + quad * 8);
  const short8 qu1a = *(const short8*)(qu + qr1 + quad * 8);
  const short8 qu1b = *(const short8*)(qu + qr1 + 32 + quad * 8);

  for (int u = wid; u < 50; u += 8) {
    if (u < 26) {
      const int m = u;
      int t = i0 + 16 * m + lm;
      if (t > 766) t = 766;
      const u16* p = rb + (size_t)t * D_ + h * DH_;
      const short8 b0 = *(const short8*)(p + quad * 8);
      const short8 b1 = *(const short8*)(p + 32 + quad * 8);
      if (m <= 24) {
        floatx4 e = (floatx4){0.f, 0.f, 0.f, 0.f};
        e = __builtin_amdgcn_mfma_f32_16x16x32_bf16(qv0a, b0, e, 0, 0, 0);
        e = __builtin_amdgcn_mfma_f32_16x16x32_bf16(qv0b, b1, e, 0, 0, 0);
#pragma unroll
        for (int r = 0; r < 4; ++r) Eb[(quad * 4 + r) * 424 + 16 * m + lm] = f2b(e[r]);
      }
      if (m >= 1) {
        floatx4 e = (floatx4){0.f, 0.f, 0.f, 0.f};
        e = __builtin_amdgcn_mfma_f32_16x16x32_bf16(qv1a, b0, e, 0, 0, 0);
        e = __builtin_amdgcn_mfma_f32_16x16x32_bf16(qv1b, b1, e, 0, 0, 0);
#pragma unroll
        for (int r = 0; r < 4; ++r) Eb[(16 + quad * 4 + r) * 424 + 16 * (m - 1) + lm] = f2b(e[r]);
      }
    } else {
      const int j = u - 26;
      const u16* p = kb + ((size_t)(b * S_ + j * 16 + lm)) * D_ + h * DH_;
      const short8 b0 = *(const short8*)(p + quad * 8);
      const short8 b1 = *(const short8*)(p + 32 + quad * 8);
      floatx4 e0 = (floatx4){0.f, 0.f, 0.f, 0.f};
      e0 = __builtin_amdgcn_mfma_f32_16x16x32_bf16(qu0a, b0, e0, 0, 0, 0);
      e0 = __builtin_amdgcn_mfma_f32_16x16x32_bf16(qu0b, b1, e0, 0, 0, 0);
      floatx4 e1 = (floatx4){0.f, 0.f, 0.f, 0.f};
      e1 = __builtin_amdgcn_mfma_f32_16x16x32_bf16(qu1a, b0, e1, 0, 0, 0);
      e1 = __builtin_amdgcn_mfma_f32_16x16x32_bf16(qu1b, b1, e1, 0, 0, 0);
#pragma unroll
      for (int r = 0; r < 4; ++r) {
        scA[(quad * 4 + r) * 396 + j * 16 + lm] = e0[r];
        scA[(16 + quad * 4 + r) * 396 + j * 16 + lm] = e1[r];
      }
    }
  }
  __syncthreads();  // barrier 1

  u16* p16 = (u16*)scA;
  {
    const int row = wid * 4 + quad;
    const int rbase = row * 424 + (row & 15) + 383;
    float v[24];
    float lmax = -1e30f;
#pragma unroll
    for (int cc = 0; cc < 24; ++cc) {
      const int c = lm + cc * 16;
      const float s = (scA[row * 396 + c] + b2f(Eb[rbase - c])) * 0.125f;
      v[cc] = s;
      lmax = fmaxf(lmax, s);
    }
#pragma unroll
    for (int m = 1; m < 16; m <<= 1) lmax = fmaxf(lmax, __shfl_xor(lmax, m));
    float lsum = 0.f;
#pragma unroll
    for (int cc = 0; cc < 24; ++cc) {
      const float e = __expf(v[cc] - lmax);
      p16[row * 792 + lm + cc * 16] = f2b(e);
      lsum += e;
    }
#pragma unroll
    for (int m = 1; m < 16; m <<= 1) lsum += __shfl_xor(lsum, m);
    if (lm == 0) rsum[row] = lsum;
  }
  __syncthreads();  // barrier 2

  {
    const int rg = wid & 1, nt = wid >> 1;
    floatx4 o = (floatx4){0.f, 0.f, 0.f, 0.f};
    const size_t vbase = ((size_t)(b * D_ + h * DH_ + nt * 16 + lm)) * S_;
    const int pbase = (rg * 16 + lm) * 792;
#pragma unroll
    for (int kk = 0; kk < 12; ++kk) {
      const short8 af = *(const short8*)(&p16[pbase + kk * 32 + quad * 8]);
      const short8 bv = *(const short8*)(vt + vbase + kk * 32 + quad * 8);
      o = __builtin_amdgcn_mfma_f32_16x16x32_bf16(af, bv, o, 0, 0, 0);
    }
#pragma unroll
    for (int r = 0; r < 4; ++r) {
      const int row = rg * 16 + quad * 4 + r;
      attn[((size_t)(b * S_ + i0 + row)) * D_ + h * DH_ + nt * 16 + lm] =
          f2b(o[r] / rsum[row]);
    }
  }
}

// ---------------- row layernorm ----------------
__global__ __launch_bounds__(256) void ln_kernel(const u16* __restrict__ y,
                                                 const u16* __restrict__ g,
                                                 const u16* __restrict__ bb,
                                                 void* __restrict__ outv,
                                                 const int* __restrict__ flag, int dual) {
  const int row = blockIdx.x * 4 + (threadIdx.x >> 6);
  const int lane = threadIdx.x & 63;
  const u16* yr = y + (size_t)row * D_;
  float vbuf[12], s = 0.f, s2 = 0.f;
#pragma unroll
  for (int i = 0; i < 12; ++i) {
    const float x = b2f(yr[lane + i * 64]);
    vbuf[i] = x;
    s += x;
    s2 += x * x;
  }
#pragma unroll
  for (int off = 32; off; off >>= 1) {
    s += __shfl_down(s, off);
    s2 += __shfl_down(s2, off);
  }
  s = __shfl(s, 0);
  s2 = __shfl(s2, 0);
  const float mean = s * (1.f / 768.f);
  const float var = s2 * (1.f / 768.f) - mean * mean;
  const float inv = rsqrtf(var + 1e-5f);
  const int f32out = dual && *flag;
#pragma unroll
  for (int i = 0; i < 12; ++i) {
    const int c = lane + i * 64;
    const float val = (vbuf[i] - mean) * inv * b2f(g[c]) + b2f(bb[c]);
    if (f32out) ((float*)outv)[(size_t)row * D_ + c] = val;
    else ((u16*)outv)[(size_t)row * D_ + c] = f2b(val);
  }
}

// ---------------- host ----------------
extern "C" void kernel_launch(void* const* d_in, const int* in_sizes, int n_in,
                              void* d_out, int out_size, void* d_ws, size_t ws_size,
                              hipStream_t stream) {
  const void* x    = d_in[0];
  const void* pe   = d_in[1];
  const void* Wq   = d_in[2];
  const void* Wk   = d_in[3];
  const void* Wv   = d_in[4];
  const void* Wr   = d_in[5];
  const void* ub   = d_in[6];
  const void* vb   = d_in[7];
  const void* Wo   = d_in[8];
  const void* ln1g = d_in[9];
  const void* ln1b = d_in[10];
  const void* ln2g = d_in[11];
  const void* ln2b = d_in[12];
  const void* W1   = d_in[13];
  const void* b1   = d_in[14];
  const void* W2   = d_in[15];
  const void* b2   = d_in[16];
  char* ws = (char*)d_ws;

  constexpr size_t O_W   = 0;
  constexpr size_t O_SM  = 15335424;
  constexpr size_t O_XB  = 15368192;
  constexpr size_t O_QU  = 24805376;
  constexpr size_t O_QV  = 34242560;
  constexpr size_t O_KB  = 43679744;
  constexpr size_t O_VT  = 53116928;
  constexpr size_t O_RB  = 62554112;
  constexpr size_t NEEDED = 63733760;

  if (ws_size < NEEDED) {
    fill_sentinel<<<(out_size + 255) / 256, 256, 0, stream>>>((u16*)d_out, out_size);
    return;
  }

  int* flag = (int*)(ws + O_SM);
  u16* ubc  = (u16*)(ws + O_SM + 128);
  u16* vbc  = (u16*)(ws + O_SM + 1664);
  u16* b1c  = (u16*)(ws + O_SM + 3200);
  u16* b2c  = (u16*)(ws + O_SM + 9344);
  u16* g1c  = (u16*)(ws + O_SM + 10880);
  u16* be1c = (u16*)(ws + O_SM + 12416);
  u16* g2c  = (u16*)(ws + O_SM + 13952);
  u16* be2c = (u16*)(ws + O_SM + 15488);

  u16* wtq = (u16*)(ws + O_W);   // wtq|wtk|wtv contiguous = fused QKV B
  u16* wtk = wtq + (size_t)D_ * D_;
  u16* wtv = wtk + (size_t)D_ * D_;
  u16* wtr = wtv + (size_t)D_ * D_;
  u16* wto = wtr + (size_t)D_ * D_;
  u16* wt1 = wto + (size_t)D_ * D_;
  u16* wt2 = wt1 + (size_t)D_ * FF_;

  u16* xb  = (u16*)(ws + O_XB);
  u16* quB = (u16*)(ws + O_QU);
  u16* qvB = (u16*)(ws + O_QV);
  u16* kbB = (u16*)(ws + O_KB);
  u16* vtB = (u16*)(ws + O_VT);
  u16* rbB = (u16*)(ws + O_RB);
  u16* peb = (u16*)d_out;          // pe lives in d_out until QKV+rproj completes
  u16* atB = (u16*)d_out;          // attn out overwrites peb afterwards (serial)
  u16* y1B = xb;
  u16* x1B = (u16*)(ws + O_VT);
  u16* ffB = xb;
  u16* y2B = x1B;

  TP tp;
  tp.src[0] = Wq; tp.src[1] = Wk; tp.src[2] = Wv; tp.src[3] = Wr; tp.src[4] = Wo;
  tp.src[5] = W1; tp.src[6] = W2;
  tp.dst[0] = wtq; tp.dst[1] = wtk; tp.dst[2] = wtv; tp.dst[3] = wtr; tp.dst[4] = wto;
  tp.dst[5] = wt1; tp.dst[6] = wt2;

  // 1) all conversions + transposes + dtype flag in one dispatch
  preamble_all<<<12705, 256, 0, stream>>>(tp, x, pe, b1, ub, vb, b2, ln1g, ln1b,
                                          ln2g, ln2b, xb, peb, b1c, ubc, vbc, b2c,
                                          g1c, be1c, g2c, be2c, flag);
  // 2) fused QKV (N=2304, coalesced vt) + r-proj in one dispatch
  gemm_qkv_rp<<<900, 256, 0, stream>>>(xb, wtq, peb, wtr, quB, qvB, kbB, vtB, rbB,
                                       ubc, vbc);
  // 3) attention -> d_out scratch
  attn_kernel<<<2304, 512, 0, stream>>>(quB, qvB, kbB, vtB, rbB, atB);
  // 4) Wo + residual
  gemm3<64, 128, 32, 64, F_RES><<<dim3(6, 96), 256, 0, stream>>>(
      atB, wto, y1B, nullptr, xb, B_ * S_, D_, D_);
  ln_kernel<<<B_ * S_ / 4, 256, 0, stream>>>(y1B, g1c, be1c, x1B, flag, 0);
  // 5) FFN1
  gemm3<128, 128, 64, 64, F_BIAS | F_RELU><<<dim3(24, 48), 256, 0, stream>>>(
      x1B, wt1, ffB, b1c, nullptr, B_ * S_, FF_, D_);
  // 6) FFN2
  gemm3<64, 128, 32, 64, F_BIAS | F_RES><<<dim3(6, 96), 256, 0, stream>>>(
      ffB, wt2, y2B, b2c, x1B, B_ * S_, D_, FF_);
  ln_kernel<<<B_ * S_ / 4, 256, 0, stream>>>(y2B, g2c, be2c, d_out, flag, 1);
}